// Round 6
// baseline (429.590 us; speedup 1.0000x reference)
//
#include <hip/hip_runtime.h>
#include <hip/hip_bf16.h>
#include <math.h>

// =====================================================================
// GraphTransformerLayer, round 6
//   - K/V interleaved per-node row (groups of 4): aggregate does ONE
//     dwordx4 gather per edge-lane instead of two dwordx2
//   - Xf (fp32 X) eliminated: LN2 residual uses bf16 Xh (saves ~77MB)
//   - #pragma unroll 2 on aggregate edge loop for load ILP
// =====================================================================

typedef __attribute__((ext_vector_type(8))) short bf16x8;
typedef __attribute__((ext_vector_type(4))) float f32x4;

#define BSHIFT 9
#define BSIZE  512

// ---------------- MFMA GEMM ----------------
// Block: 256 thr = 4 waves; tile 64 rows x 128 cols.
// A row-major (bf16, or fp32 if AF32) [M x K]; Bt transposed bf16 [Ncols x K].
// YW: blockIdx.y in {0,1,2} selects Wq/Wk/Wv; y=0 -> Cb (Q, ld 128);
//     y=1/2 -> Cb2 (KV interleaved rows of 256, K at group+0, V at group+4).
// RESB: resid pointer is bf16 (else fp32). LN/RESID assume 128 total cols.
template<int K, bool AF32, bool RELU, bool LN, bool RESID, bool RESB, bool BIAS, bool YW>
__global__ __launch_bounds__(256)
void gemm_mfma(const void* __restrict__ Ap, int lda,
               const __hip_bfloat16* __restrict__ Bt, int ldbt,
               const float* __restrict__ bias, const void* __restrict__ resid,
               const float* __restrict__ lng, const float* __restrict__ lnb,
               float* __restrict__ Cf, __hip_bfloat16* __restrict__ Cb,
               __hip_bfloat16* __restrict__ Cb2, int ldc,
               size_t bt_ystride, int N)
{
    constexpr int CK = 128;
    __shared__ unsigned short As[64 * 136];
    __shared__ unsigned short Bs[128 * 136];

    const int tid  = threadIdx.x;
    const int row0 = blockIdx.x * 64;
    int col0 = 0;
    if (YW) Bt += blockIdx.y * bt_ystride;
    else    col0 = blockIdx.y * 128;

    const int wave = tid >> 6, lane = tid & 63;
    const int quad = lane >> 4, l15 = lane & 15;

    f32x4 acc[8];
    #pragma unroll
    for (int t = 0; t < 8; ++t) acc[t] = (f32x4)0.f;

    for (int kc = 0; kc < K; kc += CK) {
        #pragma unroll
        for (int it = 0; it < 4; ++it) {          // A: 64 x 128
            int i = tid + it * 256;
            int r = i >> 4, kb = i & 15;
            int rg = row0 + r; if (rg > N - 1) rg = N - 1;
            if (AF32) {
                const float* Af = (const float*)Ap;
                const float4 f0 = *(const float4*)&Af[(size_t)rg * lda + kc + kb * 8];
                const float4 f1 = *(const float4*)&Af[(size_t)rg * lda + kc + kb * 8 + 4];
                __hip_bfloat162 b01 = __float22bfloat162_rn(make_float2(f0.x, f0.y));
                __hip_bfloat162 b23 = __float22bfloat162_rn(make_float2(f0.z, f0.w));
                __hip_bfloat162 b45 = __float22bfloat162_rn(make_float2(f1.x, f1.y));
                __hip_bfloat162 b67 = __float22bfloat162_rn(make_float2(f1.z, f1.w));
                uint4 u;
                u.x = *(unsigned*)&b01; u.y = *(unsigned*)&b23;
                u.z = *(unsigned*)&b45; u.w = *(unsigned*)&b67;
                *(uint4*)&As[r * 136 + kb * 8] = u;
            } else {
                const __hip_bfloat16* Ab = (const __hip_bfloat16*)Ap;
                *(uint4*)&As[r * 136 + kb * 8] =
                    *(const uint4*)&Ab[(size_t)rg * lda + kc + kb * 8];
            }
        }
        #pragma unroll
        for (int it = 0; it < 8; ++it) {          // Bt: 128 x 128
            int i = tid + it * 256;
            int r = i >> 4, kb = i & 15;
            *(uint4*)&Bs[r * 136 + kb * 8] =
                *(const uint4*)&Bt[(size_t)(col0 + r) * ldbt + kc + kb * 8];
        }
        __syncthreads();
        const unsigned short* ap = &As[(wave * 16 + l15) * 136 + quad * 8];
        const unsigned short* bp = &Bs[l15 * 136 + quad * 8];
        #pragma unroll
        for (int ks = 0; ks < 4; ++ks) {
            bf16x8 a = *(const bf16x8*)(ap + ks * 32);
            #pragma unroll
            for (int t = 0; t < 8; ++t) {
                bf16x8 b = *(const bf16x8*)(bp + t * 16 * 136 + ks * 32);
                acc[t] = __builtin_amdgcn_mfma_f32_16x16x32_bf16(a, b, acc[t], 0, 0, 0);
            }
        }
        __syncthreads();
    }

    const int rbase = row0 + wave * 16 + quad * 4;

    float vals[8][4];
    #pragma unroll
    for (int t = 0; t < 8; ++t) {
        float bv = BIAS ? bias[col0 + t * 16 + l15] : 0.f;
        #pragma unroll
        for (int i = 0; i < 4; ++i) vals[t][i] = acc[t][i] + bv;
    }

    if (YW) {   // QKV epilogue: y=0 -> Q; y=1/2 -> interleaved KV
        const int y = blockIdx.y;
        #pragma unroll
        for (int i = 0; i < 4; ++i) {
            int row = rbase + i;
            if (row >= N) continue;
            if (y == 0) {
                #pragma unroll
                for (int t = 0; t < 8; ++t)
                    Cb[(size_t)row * 128 + t * 16 + l15] = __float2bfloat16(vals[t][i]);
            } else {
                const int vo = (y == 2) ? 4 : 0;
                #pragma unroll
                for (int t = 0; t < 8; ++t) {
                    int c = t * 16 + l15;
                    Cb2[(size_t)row * 256 + ((c >> 2) << 3) + (c & 3) + vo] =
                        __float2bfloat16(vals[t][i]);
                }
            }
        }
        return;
    }

    if (RESID) {
        #pragma unroll
        for (int i = 0; i < 4; ++i) {
            int row = rbase + i;
            if (row < N) {
                if (RESB) {
                    const __hip_bfloat16* rb = (const __hip_bfloat16*)resid;
                    #pragma unroll
                    for (int t = 0; t < 8; ++t)
                        vals[t][i] += __bfloat162float(rb[(size_t)row * 128 + t * 16 + l15]);
                } else {
                    const float* rf = (const float*)resid;
                    #pragma unroll
                    for (int t = 0; t < 8; ++t)
                        vals[t][i] += rf[(size_t)row * 128 + t * 16 + l15];
                }
            }
        }
    }
    if (RELU) {
        #pragma unroll
        for (int t = 0; t < 8; ++t)
            #pragma unroll
            for (int i = 0; i < 4; ++i) vals[t][i] = fmaxf(vals[t][i], 0.f);
    }
    if (LN) {
        #pragma unroll
        for (int i = 0; i < 4; ++i) {
            float s = 0.f, sq = 0.f;
            #pragma unroll
            for (int t = 0; t < 8; ++t) { float v = vals[t][i]; s += v; sq += v * v; }
            s  += __shfl_xor(s, 1);  s  += __shfl_xor(s, 2);
            s  += __shfl_xor(s, 4);  s  += __shfl_xor(s, 8);
            sq += __shfl_xor(sq, 1); sq += __shfl_xor(sq, 2);
            sq += __shfl_xor(sq, 4); sq += __shfl_xor(sq, 8);
            float m  = s * (1.f / 128.f);
            float rs = rsqrtf(sq * (1.f / 128.f) - m * m + 1e-5f);
            #pragma unroll
            for (int t = 0; t < 8; ++t) {
                float g = lng[t * 16 + l15], b = lnb[t * 16 + l15];
                vals[t][i] = (vals[t][i] - m) * rs * g + b;
            }
        }
    }
    #pragma unroll
    for (int i = 0; i < 4; ++i) {
        int row = rbase + i;
        if (row >= N) continue;
        if (Cf) {
            #pragma unroll
            for (int t = 0; t < 8; ++t)
                Cf[(size_t)row * ldc + col0 + t * 16 + l15] = vals[t][i];
        }
        if (Cb) {
            #pragma unroll
            for (int t = 0; t < 8; ++t)
                Cb[(size_t)row * ldc + col0 + t * 16 + l15] = __float2bfloat16(vals[t][i]);
        }
    }
}

// ---------------- weight cast+transpose ----------------
struct WArgs {
    const float* src[6];
    __hip_bfloat16* dst[6];
    int R[6], C[6];
};
__global__ __launch_bounds__(256)
void cast_w(WArgs wa)
{
    int w = blockIdx.y;
    int R = wa.R[w], C = wa.C[w];
    int i = blockIdx.x * 256 + threadIdx.x;
    if (i >= R * C) return;
    int sh = (C == 256) ? 8 : 7;
    int r = i >> sh, c = i & (C - 1);
    wa.dst[w][(size_t)c * R + r] = __float2bfloat16(wa.src[w][i]);
}

// ---------------- two-level bucketed sort of edges by dst ----------------
__global__ __launch_bounds__(256)
void bucket_hist(const int* __restrict__ dst, int* __restrict__ bCnt,
                 int E, int chunk, int NB)
{
    __shared__ int bh[256];
    const int t = threadIdx.x;
    bh[t] = 0;
    __syncthreads();
    const int s0 = blockIdx.x * chunk;
    const int s1 = min(E, s0 + chunk);
    for (int i = s0 + t; i < s1; i += 256)
        atomicAdd(&bh[dst[i] >> BSHIFT], 1);
    __syncthreads();
    if (t < NB && bh[t]) atomicAdd(&bCnt[t], bh[t]);
}

__global__ __launch_bounds__(256)
void bucket_scan(const int* __restrict__ bCnt, int* __restrict__ bBase,
                 int* __restrict__ gCur, int* __restrict__ rowStart,
                 int N, int E, int NB)
{
    __shared__ int wsum[4];
    const int t = threadIdx.x, lane = t & 63, wv = t >> 6;
    int v = (t < NB) ? bCnt[t] : 0;
    const int s = v;
    for (int off = 1; off < 64; off <<= 1) {
        int u = __shfl_up(v, off);
        if (lane >= off) v += u;
    }
    if (lane == 63) wsum[wv] = v;
    __syncthreads();
    int add = 0;
    for (int w = 0; w < wv; ++w) add += wsum[w];
    const int excl = v + add - s;
    if (t <= NB) bBase[t] = excl;
    if (t < NB)  gCur[t]  = excl;
    if (t == 0)  rowStart[N] = E;
}

__global__ __launch_bounds__(256)
void partition_kernel(const int* __restrict__ src, const int* __restrict__ dst,
                      int* __restrict__ gCur, uint2* __restrict__ P,
                      int E, int chunk, int NB)
{
    __shared__ int ch[256];
    __shared__ int cur[256];
    const int t = threadIdx.x;
    ch[t] = 0;
    __syncthreads();
    const int s0 = blockIdx.x * chunk;
    const int s1 = min(E, s0 + chunk);
    for (int i = s0 + t; i < s1; i += 256)
        atomicAdd(&ch[dst[i] >> BSHIFT], 1);
    __syncthreads();
    if (t < NB) {
        int c = ch[t];
        cur[t] = c ? atomicAdd(&gCur[t], c) : 0;
    }
    __syncthreads();
    for (int i = s0 + t; i < s1; i += 256) {
        int d = dst[i];
        int pos = atomicAdd(&cur[d >> BSHIFT], 1);
        P[pos] = make_uint2((unsigned)src[i], (unsigned)d);
    }
}

__global__ __launch_bounds__(256)
void bucket_scatter(const uint2* __restrict__ P, const int* __restrict__ bBase,
                    int* __restrict__ rowStart, int* __restrict__ esrc, int N)
{
    __shared__ int hist[BSIZE];
    __shared__ int cur[BSIZE];
    __shared__ int wsum[4];

    const int b  = blockIdx.x;
    const int t  = threadIdx.x;
    const int d0 = b << BSHIFT;
    const int bb  = bBase[b];
    const int cnt = bBase[b + 1] - bb;

    hist[t] = 0; hist[t + 256] = 0;
    __syncthreads();
    for (int i = t; i < cnt; i += 256)
        atomicAdd(&hist[(int)P[bb + i].y - d0], 1);
    __syncthreads();

    {
        const int a0 = hist[2 * t], a1 = hist[2 * t + 1];
        int v = a0 + a1;
        const int s = v;
        const int lane = t & 63, wv = t >> 6;
        for (int off = 1; off < 64; off <<= 1) {
            int u = __shfl_up(v, off);
            if (lane >= off) v += u;
        }
        if (lane == 63) wsum[wv] = v;
        __syncthreads();
        int add = 0;
        for (int w = 0; w < wv; ++w) add += wsum[w];
        const int exclT = v + add - s;
        cur[2 * t]     = exclT;
        cur[2 * t + 1] = exclT + a0;
    }
    __syncthreads();
    for (int i = t; i < BSIZE; i += 256) {
        int d = d0 + i;
        if (d < N) rowStart[d] = bb + cur[i];
    }
    __syncthreads();
    for (int i = t; i < cnt; i += 256) {
        uint2 p = P[bb + i];
        int pos = atomicAdd(&cur[(int)p.y - d0], 1);
        esrc[bb + pos] = (int)p.x;
    }
}

// ---------------- aggregation: wave = 2 edges (32 lanes each) ----------------
// KV rows: 32 groups of [K[4i..4i+4) | V[4i..4i+4)] -> lane l5 loads uint4.
__global__ __launch_bounds__(256)
void aggregate_kernel(__hip_bfloat16* __restrict__ Q,
                      const __hip_bfloat16* __restrict__ KV,
                      const int* __restrict__ esrc,
                      const int* __restrict__ rowStart, int N)
{
    const int lane = threadIdx.x & 63;
    const int wid  = threadIdx.x >> 6;
    const int d    = blockIdx.x * 4 + wid;
    if (d >= N) return;

    const int l5   = lane & 31;
    const int half = lane >> 5;

    const uint4* KV4 = (const uint4*)KV;
    uint2*       Q2  = (uint2*)Q;

    const uint2 qraw = Q2[(unsigned)d * 32u + (unsigned)l5];
    const float q0 = __uint_as_float(qraw.x << 16);
    const float q1 = __uint_as_float(qraw.x & 0xffff0000u);
    const float q2 = __uint_as_float(qraw.y << 16);
    const float q3 = __uint_as_float(qraw.y & 0xffff0000u);

    const int beg = rowStart[d];
    const int end = rowStart[d + 1];

    float a0 = 0.f, a1 = 0.f, a2 = 0.f, a3 = 0.f, zacc = 0.f;
    const float S = 0.36067376022224085f;  // 0.25 * log2(e)
    const float C = 7.2134752044448170f;   // 5 * log2(e)

    for (int base = beg; base < end; base += 64) {
        int n = end - base; if (n > 64) n = 64;
        int mysrc = (lane < n) ? esrc[base + lane] : 0;
        const int nf = n >> 1;
        int bidx = half;
        #pragma unroll 2
        for (int j = 0; j < nf; ++j, bidx += 2) {
            const int s = __shfl(mysrc, bidx);
            const uint4 kv = KV4[(unsigned)s * 32u + (unsigned)l5];
            float p = __uint_as_float(kv.x << 16)         * q0
                    + __uint_as_float(kv.x & 0xffff0000u) * q1
                    + __uint_as_float(kv.y << 16)         * q2
                    + __uint_as_float(kv.y & 0xffff0000u) * q3;
            p += __shfl_xor(p, 1);
            p += __shfl_xor(p, 2);
            const float tt = fminf(C, fmaxf(-C, p * S));
            const float se = exp2f(tt);
            a0 += __uint_as_float(kv.z << 16)         * se;
            a1 += __uint_as_float(kv.z & 0xffff0000u) * se;
            a2 += __uint_as_float(kv.w << 16)         * se;
            a3 += __uint_as_float(kv.w & 0xffff0000u) * se;
            zacc += se;
        }
        if (n & 1) {
            const int s = __shfl(mysrc, n - 1);
            const uint4 kv = KV4[(unsigned)s * 32u + (unsigned)l5];
            float p = __uint_as_float(kv.x << 16)         * q0
                    + __uint_as_float(kv.x & 0xffff0000u) * q1
                    + __uint_as_float(kv.y << 16)         * q2
                    + __uint_as_float(kv.y & 0xffff0000u) * q3;
            p += __shfl_xor(p, 1);
            p += __shfl_xor(p, 2);
            const float tt = fminf(C, fmaxf(-C, p * S));
            float se = exp2f(tt);
            se = half ? 0.f : se;
            a0 += __uint_as_float(kv.z << 16)         * se;
            a1 += __uint_as_float(kv.z & 0xffff0000u) * se;
            a2 += __uint_as_float(kv.w << 16)         * se;
            a3 += __uint_as_float(kv.w & 0xffff0000u) * se;
            zacc += se;
        }
    }

    a0 += __shfl_xor(a0, 32); a1 += __shfl_xor(a1, 32);
    a2 += __shfl_xor(a2, 32); a3 += __shfl_xor(a3, 32);
    zacc += __shfl_xor(zacc, 32);

    if (half == 0) {
        const float inv = 1.0f / (zacc + 1e-6f);
        __hip_bfloat162 p0 = __float22bfloat162_rn(make_float2(a0 * inv, a1 * inv));
        __hip_bfloat162 p1 = __float22bfloat162_rn(make_float2(a2 * inv, a3 * inv));
        uint2 o;
        o.x = *(unsigned*)&p0;
        o.y = *(unsigned*)&p1;
        Q2[(unsigned)d * 32u + (unsigned)l5] = o;
    }
}

// =====================================================================
extern "C" void kernel_launch(void* const* d_in, const int* in_sizes, int n_in,
                              void* d_out, int out_size, void* d_ws, size_t ws_size,
                              hipStream_t stream)
{
    const float* h    = (const float*)d_in[0];
    const int*   src  = (const int*)  d_in[1];
    const int*   dst  = (const int*)  d_in[2];
    const float* Wq   = (const float*)d_in[3];
    const float* Wk   = (const float*)d_in[4];
    const float* Wv   = (const float*)d_in[5];
    const float* Wo   = (const float*)d_in[6];
    const float* bo   = (const float*)d_in[7];
    const float* ln1g = (const float*)d_in[8];
    const float* ln1b = (const float*)d_in[9];
    const float* W1   = (const float*)d_in[10];
    const float* b1   = (const float*)d_in[11];
    const float* W2   = (const float*)d_in[12];
    const float* b2   = (const float*)d_in[13];
    const float* ln2g = (const float*)d_in[14];
    const float* ln2b = (const float*)d_in[15];

    const int N = in_sizes[0] / 128;
    const int E = in_sizes[1];
    const int NB = (N + BSIZE - 1) >> BSHIFT;

    // ---- workspace layout ----
    __hip_bfloat16* Qh  = (__hip_bfloat16*)d_ws;       // N*128 (h_attn after agg)
    __hip_bfloat16* KVh = Qh + (size_t)N * 128;        // N*256 interleaved K/V
    __hip_bfloat16* Xh  = KVh + (size_t)N * 256;       // N*128
    __hip_bfloat16* Wt  = Xh + (size_t)N * 128;        // 131072 bf16
    __hip_bfloat16* Wqt = Wt;
    __hip_bfloat16* Wkt = Wqt + 16384;
    __hip_bfloat16* Wvt = Wkt + 16384;
    __hip_bfloat16* Wot = Wvt + 16384;
    __hip_bfloat16* W1t = Wot + 16384;        // [256][128]
    __hip_bfloat16* W2t = W1t + 32768;        // [128][256]
    int* ib       = (int*)(W2t + 32768);
    int* bCnt     = ib;                       // 256
    int* bBase    = ib + 256;                 // 257
    int* gCur     = ib + 514;                 // 256
    int* rowStart = ib + 770;                 // N+1
    int* esrc     = ib + 770 + N + 2;         // E
    uint2* P      = (uint2*)(esrc + E);       // E pairs
    __hip_bfloat16* Th = KVh;                 // N*256 overlay (KV dead post-agg)

    const dim3 blk(256);
    const int  nb    = (N + 63) / 64;
    const int  chunk = (E + 255) / 256;

    // ---- weight cast+transpose ----
    WArgs wa;
    wa.src[0] = Wq; wa.src[1] = Wk; wa.src[2] = Wv; wa.src[3] = Wo; wa.src[4] = W1; wa.src[5] = W2;
    wa.dst[0] = Wqt; wa.dst[1] = Wkt; wa.dst[2] = Wvt; wa.dst[3] = Wot; wa.dst[4] = W1t; wa.dst[5] = W2t;
    wa.R[0] = wa.R[1] = wa.R[2] = wa.R[3] = 128; wa.R[4] = 128; wa.R[5] = 256;
    wa.C[0] = wa.C[1] = wa.C[2] = wa.C[3] = 128; wa.C[4] = 256; wa.C[5] = 128;
    cast_w<<<dim3(128, 6), blk, 0, stream>>>(wa);

    // ---- QKV: y=0 -> Qh, y=1/2 -> interleaved KVh ----
    gemm_mfma<128,true,false,false,false,false,false,true><<<dim3(nb, 3), blk, 0, stream>>>(
        h, 128, Wqt, 128, nullptr, nullptr, nullptr, nullptr,
        nullptr, Qh, KVh, 128, (size_t)16384, N);

    // ---- bucketed sort of edges by dst ----
    hipMemsetAsync(bCnt, 0, 256 * sizeof(int), stream);
    bucket_hist<<<dim3(256), blk, 0, stream>>>(dst, bCnt, E, chunk, NB);
    bucket_scan<<<dim3(1), blk, 0, stream>>>(bCnt, bBase, gCur, rowStart, N, E, NB);
    partition_kernel<<<dim3(256), blk, 0, stream>>>(src, dst, gCur, P, E, chunk, NB);
    bucket_scatter<<<dim3(NB), blk, 0, stream>>>(P, bBase, rowStart, esrc, N);

    // ---- aggregate (writes h_attn bf16 into Qh) ----
    aggregate_kernel<<<dim3((N + 3) / 4), blk, 0, stream>>>(Qh, KVh, esrc, rowStart, N);

    // ---- X = LN1(h + h_attn@Wo + bo) -> bf16 Xh only ----
    gemm_mfma<128,false,false,true,true,false,true,false><<<dim3(nb, 1), blk, 0, stream>>>(
        Qh, 128, Wot, 128, bo, h, ln1g, ln1b, nullptr, Xh, nullptr, 128, 0, N);

    // ---- T = relu(X@W1 + b1) -> bf16 ----
    gemm_mfma<128,false,true,false,false,false,true,false><<<dim3(nb, 2), blk, 0, stream>>>(
        Xh, 128, W1t, 128, b1, nullptr, nullptr, nullptr, nullptr, Th, nullptr, 256, 0, N);

    // ---- out = LN2(Xh + T@W2 + b2) -> fp32 (bf16 residual) ----
    gemm_mfma<256,false,false,true,true,true,true,false><<<dim3(nb, 1), blk, 0, stream>>>(
        Th, 256, W2t, 256, b2, Xh, ln2g, ln2b, (float*)d_out, nullptr, nullptr, 128, 0, N);
}